// Round 1
// baseline (373.227 us; speedup 1.0000x reference)
//
#include <hip/hip_runtime.h>
#include <hip/hip_bf16.h>
#include <type_traits>

typedef __attribute__((ext_vector_type(8))) short short8;
typedef __attribute__((ext_vector_type(16))) float f32x16;

// ---------------- workspace layout (bytes) ----------------
// Xpad bf16 NHWC [32][58][58][256]                    : 55,115,776 B
// Wq   bf16 32x32-frag layout [4][2][9][8][...]       :  4,718,592 B
// pooled f32 [32][256] (SUMS, zeroed by memset)       :     32,768 B
// idx  int [32]                                       :        128 B
#define XPAD_OFF   0u
#define WQ_OFF     55115776u
#define POOL_OFF   59834368u
#define IDX_OFF    59867136u

__device__ __forceinline__ void gl_lds16(const void* g, void* l) {
  __builtin_amdgcn_global_load_lds(
      (const __attribute__((address_space(1))) unsigned int*)g,
      (__attribute__((address_space(3))) unsigned int*)l, 16, 0, 0);
}

// ---- 1. fc1/relu/fc2 + argmax: one block per sample ----
__global__ __launch_bounds__(128) void fc_argmax_kernel(
    const float* __restrict__ pooled, const float* __restrict__ w_fc1,
    const float* __restrict__ w_fc2, const float* __restrict__ b_fc2,
    float* __restrict__ raw_out, int* __restrict__ idx) {
  __shared__ float h[65];
  __shared__ float raws[4];
  const int b = blockIdx.x, t = threadIdx.x;
  if (t < 65) {
    float s = 0.f;
    const float* pb = pooled + b * 256;
    const float* wr = w_fc1 + t * 256;
    for (int c = 0; c < 256; ++c) s += pb[c] * wr[c];
    s *= (1.0f / 3136.0f);
    h[t] = s > 0.f ? s : 0.f;
  }
  __syncthreads();
  if (t < 4) {
    float s = b_fc2[t];
    const float* wr = w_fc2 + t * 65;
    for (int j = 0; j < 65; ++j) s += h[j] * wr[j];
    raws[t] = s;
    raw_out[b * 4 + t] = s;
  }
  __syncthreads();
  if (t == 0) {
    int best = 0; float bv = raws[0];
    for (int k = 1; k < 4; ++k) if (raws[k] > bv) { bv = raws[k]; best = k; }
    idx[b] = best;
  }
}

// ---- 2. LSQ quantize + reorder to 32x32x16-fragment-ready layout ----
// slab (k,ot): granule = (tap*64 + cbh*8 + wm*4 + octile*2 + s)*64 + lane
// lane carries oc%32 (lane&31) and ch-half (lane>>5); 8 ch elems per granule.
__global__ __launch_bounds__(256) void quant_kernel(
    const float* __restrict__ weight, const float* __restrict__ alpha,
    __hip_bfloat16* __restrict__ Wq) {
  const unsigned d = blockIdx.x * 256u + threadIdx.x;   // 0 .. 2,359,295
  const unsigned cl   = d & 7u;
  const unsigned g    = d >> 3;          // granule [0, 294912)
  const unsigned lane = g & 63u;
  const unsigned u    = g >> 6;          // unit [0, 4608)
  const unsigned low  = u & 63u;
  const unsigned s      = low & 1u;
  const unsigned octile = (low >> 1) & 1u;
  const unsigned wm     = (low >> 2) & 1u;
  const unsigned cbh    = (low >> 3) & 7u;
  const unsigned t6   = u >> 6;          // slabq*9 + tap, [0, 72)
  const unsigned tap  = t6 % 9u;
  const unsigned q    = t6 / 9u;
  const unsigned ot   = q & 1u;
  const unsigned k    = q >> 1;
  const unsigned oc = ot * 128u + wm * 64u + octile * 32u + (lane & 31u);
  const unsigned ch = cbh * 32u + s * 16u + (lane >> 5) * 8u + cl;
  const float a = alpha[k];
  float v = weight[(size_t)k * 589824u + oc * 2304u + ch * 9u + tap] / a;
  if (oc == 0u && ch == 0u && tap == 0u) {  // only flat element [k][0] clamped
    if (k == 0u)      v = fminf(fmaxf(v, -2.f), 1.f);
    else if (k == 1u) v = fminf(fmaxf(v, -4.f), 3.f);
    else if (k == 2u) v = fminf(fmaxf(v, -8.f), 7.f);
  }
  Wq[d] = __float2bfloat16(rintf(v) * a);
}

// ---- 3. pad + NCHW->NHWC + bf16 via LDS transpose, fused global-avg-pool ----
// Xpad rows 58 (y'), cols 58 (x' = 0..57; input col x'-1), 256 ch.
// float4 global loads; LDS stride 133 (132 gave ~7-way write conflicts: bank
// step 4*px; 133 -> step 5, coprime-ish with 32).
__global__ __launch_bounds__(256) void padx_kernel(const float* __restrict__ x,
                                                   __hip_bfloat16* __restrict__ Xpad,
                                                   float* __restrict__ pooled) {
  __shared__ float T[56 * 133];   // [px][c_local], stride 133
  const int yp = blockIdx.x;
  const int c0 = blockIdx.y * 128;
  const int b  = blockIdx.z;
  const int tid = threadIdx.x;
  __hip_bfloat16* orow = Xpad + ((size_t)(b * 58 + yp) * 58) * 256 + c0;
  const short8 zero8 = (short8){0, 0, 0, 0, 0, 0, 0, 0};
  const bool rowin = (yp >= 1 && yp <= 56);
  if (rowin) {
    const float4* xb4 = (const float4*)(x + (((size_t)b * 256 + c0) * 56 + (yp - 1)) * 56);
    for (int i = tid; i < 1792; i += 256) {             // 128ch x 14 float4
      const int cl = i / 14, p4 = i - cl * 14;
      const float4 v = xb4[(size_t)cl * 784 + p4];
      float* Tp = &T[(p4 * 4) * 133 + cl];
      Tp[0] = v.x; Tp[133] = v.y; Tp[266] = v.z; Tp[399] = v.w;
    }
    __syncthreads();
    if (tid < 128) {                                   // fused pooling
      float s = 0.f;
      for (int px = 0; px < 56; ++px) s += T[px * 133 + tid];
      atomicAdd(pooled + b * 256 + c0 + tid, s);
    }
    for (int i = tid; i < 896; i += 256) {             // data cols xp=1..56
      const int px = i >> 4, cg = (i & 15) * 8;
      union { short8 v; __hip_bfloat16 e[8]; } u;
      #pragma unroll
      for (int r = 0; r < 8; ++r) u.e[r] = __float2bfloat16(T[px * 133 + cg + r]);
      *(short8*)&orow[(px + 1) * 256 + cg] = u.v;
    }
    for (int i = tid; i < 32; i += 256) {              // pad cols xp=0,57
      const int cg = (i & 15) * 8;
      const int xp = (i >> 4) ? 57 : 0;
      *(short8*)&orow[xp * 256 + cg] = zero8;
    }
  } else {                                             // border rows y'=0,57
    for (int i = tid; i < 58 * 16; i += 256) {
      const int xp = i >> 4, cg = (i & 15) * 8;
      *(short8*)&orow[xp * 256 + cg] = zero8;
    }
  }
}

// ---- 4. conv as implicit GEMM, bf16 MFMA 32x32x16 ----
// v2: ot fused. Block 512 thr (8 waves), grid (b=32, pt=14): 256oc x 256px
// (4 rows x 64 cols). Wave tile 128oc x 64px (1 row x 2 colgroups):
// acc[4][2] f32x16 = 128 AGPR; each ds_read_b128 B-fragment feeds 4 MFMA
// (was 2) -> LDS read cycles per MFMA halved. X staged once per (pt,b)
// -> HBM X fetch halved vs ot-split grid. W: 2-deep register ring (t+1
// prefetch, ~1024cyc MFMA shadow covers L2); ring parity made compile-time
// via per-parity chunk instantiation (9 taps/chunk flips parity each chunk).
// grid.x = b so all pt-blocks of a sample share XCD b%8 (halo + W L2 reuse).
__global__ __launch_bounds__(512, 2) void conv_kernel(
    const __hip_bfloat16* __restrict__ Xpad, const __hip_bfloat16* __restrict__ Wq,
    const int* __restrict__ idx, const float* __restrict__ bias_w,
    float* __restrict__ out) {
  // per buffer: 6 rows x 58 px x 4 granules = 1392 data granules; padded to
  // 1424 granules (22784 B) for discarded-lane reads (col<=65) + staging tail.
  __shared__ __attribute__((aligned(16))) __hip_bfloat16 Xs[22784];

  const int tid = threadIdx.x;
  const int lane = tid & 63;
  const int w = tid >> 6;        // 0..7
  const int wn = w & 3;          // px row within block tile
  const int wm = w >> 2;         // oc half (= slab ot)

  const int b  = blockIdx.x;     // 0..31
  const int pt = blockIdx.y;     // 0..13 -> output rows 4*pt..4*pt+3
  const int Y0 = pt * 4;
  const int kb = idx[b];

  const __hip_bfloat16* xb = Xpad + (size_t)b * (58 * 58 * 256);
  const short8* Wk = (const short8*)Wq + (size_t)(kb * 2 + wm) * 36864;

  f32x16 acc[4][2];
  #pragma unroll
  for (int i = 0; i < 4; ++i)
    #pragma unroll
    for (int j = 0; j < 2; ++j)
      acc[i][j] = (f32x16){0,0,0,0,0,0,0,0,0,0,0,0,0,0,0,0};

  const int nlo = lane & 31;     // oc%32 (A) / px col (B)
  const int khalf = lane >> 5;   // ch-half selector

  // one staging segment (64 granules) of chunk cbn into buffer bufsel
  auto stageseg = [&](int cbn, int bufsel, int k) {
    int sidx = k * 64 + lane;
    int p = sidx >> 2;
    if (p > 347) p = 347;                   // tail dups -> pad granules
    const int gsel = (sidx & 3) ^ ((p >> 1) & 3);
    const int r = p / 58, xc = p - r * 58;
    gl_lds16(xb + (((Y0 + r) * 58 + xc) * 256 + cbn * 32 + gsel * 8),
             (char*)Xs + bufsel * 22784 + k * 1024);
  };

  for (int k = w; k < 22; k += 8) stageseg(0, 0, k);   // chunk 0 burst
  __syncthreads();

  // W register ring, depth 2: afr[par][i*2+s], i = oc-tile 0..3
  short8 afr[2][8];
  #pragma unroll
  for (int i2 = 0; i2 < 4; ++i2)
    #pragma unroll
    for (int s2 = 0; s2 < 2; ++s2)
      afr[0][i2 * 2 + s2] = Wk[(i2 >> 1) * 256 + (i2 & 1) * 128 + s2 * 64 + lane];

  auto chunk = [&](int cbh, auto parc) {
    constexpr int PAR = decltype(parc)::value;   // == cbh & 1 (compile-time)
    const __hip_bfloat16* cur = Xs + PAR * 11392;
    const int nb = PAR ^ 1;
    #pragma unroll
    for (int t = 0; t < 9; ++t) {
      const int dy = t / 3, dx = t - dy * 3;
      // X staging for next chunk spread over taps 0..2 (barrier is ~6 taps
      // after last issue -> vmcnt drain free)
      if (cbh < 7) {
        if (t < 2) stageseg(cbh + 1, nb, w + 8 * t);
        else if (t == 2 && w < 6) stageseg(cbh + 1, nb, w + 16);
      }
      // W prefetch for t+1 into the other ring bank
      if (cbh < 7 || t < 8) {
        const int tap2 = (t + 1) % 9, cb2 = cbh + (t + 1) / 9;
        #pragma unroll
        for (int i2 = 0; i2 < 4; ++i2)
          #pragma unroll
          for (int s2 = 0; s2 < 2; ++s2)
            afr[(t + 1 + PAR) & 1][i2 * 2 + s2] =
                Wk[tap2 * 4096 + cb2 * 512 + (i2 >> 1) * 256 + (i2 & 1) * 128 +
                   s2 * 64 + lane];
      }
      // compute: 2 K16-steps x 2 colgroups; each B read feeds 4 MFMA
      #pragma unroll
      for (int s = 0; s < 2; ++s) {
        #pragma unroll
        for (int j = 0; j < 2; ++j) {
          const int row = wn + dy;
          const int col = j * 32 + nlo + dx;
          const int p = row * 58 + col;
          const int slot = p * 4 + ((s * 2 + khalf) ^ ((p >> 1) & 3));
          const short8 bfr = *(const short8*)&cur[slot * 8];
          #pragma unroll
          for (int i = 0; i < 4; ++i)
            acc[i][j] = __builtin_amdgcn_mfma_f32_32x32x16_bf16(
                afr[(t + PAR) & 1][i * 2 + s], bfr, acc[i][j], 0, 0, 0);
        }
      }
    }
    __syncthreads();   // next buffer staged; cur readers done
  };

  for (int c2 = 0; c2 < 8; c2 += 2) {
    chunk(c2,     std::integral_constant<int, 0>{});
    chunk(c2 + 1, std::integral_constant<int, 1>{});
  }

  // epilogue: 32x32 C/D: col=lane&31, row=(reg&3)+8*(reg>>2)+4*(lane>>5)
  const float* biasb = bias_w + kb * 256;
  const int y = Y0 + wn;
  #pragma unroll
  for (int j = 0; j < 2; ++j) {
    const int xcol = j * 32 + nlo;
    if (xcol < 56) {
      #pragma unroll
      for (int i = 0; i < 4; ++i) {
        #pragma unroll
        for (int reg = 0; reg < 16; ++reg) {
          const int rowr = (reg & 3) + 8 * (reg >> 2) + 4 * khalf;
          const int oc = wm * 128 + i * 32 + rowr;
          out[(((size_t)b * 256 + oc) * 56 + y) * 56 + xcol] =
              acc[i][j][reg] + biasb[oc];
        }
      }
    }
  }
}

extern "C" void kernel_launch(void* const* d_in, const int* in_sizes, int n_in,
                              void* d_out, int out_size, void* d_ws, size_t ws_size,
                              hipStream_t stream) {
  const float* x      = (const float*)d_in[0];
  const float* w_fc1  = (const float*)d_in[1];
  const float* w_fc2  = (const float*)d_in[2];
  const float* b_fc2  = (const float*)d_in[3];
  const float* alpha  = (const float*)d_in[4];
  const float* weight = (const float*)d_in[5];
  const float* bias_w = (const float*)d_in[6];

  float* out = (float*)d_out;
  float* raw_out = out + (size_t)32 * 256 * 56 * 56;  // tuple: (out, raw)

  char* ws = (char*)d_ws;
  __hip_bfloat16* Xpad = (__hip_bfloat16*)(ws + XPAD_OFF);
  __hip_bfloat16* Wq   = (__hip_bfloat16*)(ws + WQ_OFF);
  float* pooled        = (float*)(ws + POOL_OFF);
  int* idx             = (int*)(ws + IDX_OFF);

  hipMemsetAsync(pooled, 0, 32 * 256 * sizeof(float), stream);
  padx_kernel<<<dim3(58, 2, 32), 256, 0, stream>>>(x, Xpad, pooled);
  quant_kernel<<<9216, 256, 0, stream>>>(weight, alpha, Wq);
  fc_argmax_kernel<<<32, 128, 0, stream>>>(pooled, w_fc1, w_fc2, b_fc2, raw_out, idx);
  conv_kernel<<<dim3(32, 14), 512, 0, stream>>>(Xpad, Wq, idx, bias_w, out);
}